// Round 8
// baseline (961.481 us; speedup 1.0000x reference)
//
#include <hip/hip_runtime.h>

typedef _Float16 f16;
typedef _Float16 f16x8 __attribute__((ext_vector_type(8)));
typedef _Float16 f16x4 __attribute__((ext_vector_type(4)));
typedef float    f32x4 __attribute__((ext_vector_type(4)));

// Problem constants: B=32, T=128, L=512, D=256, M=4, VOCAB=32000, HOPS=3
// DTYPE (HW-validated round 4): ALL float inputs/outputs are fp32.

__device__ __forceinline__ float fsig(float x){ return 1.0f/(1.0f + __expf(-x)); }
__device__ __forceinline__ float ftanh(float x){ return 2.0f/(1.0f + __expf(-2.0f*x)) - 1.0f; }

// ---------------------------------------------------------------------------
__global__ void k_zero(float* out){
  int i = blockIdx.x*256 + threadIdx.x;
  if (i < 24576) out[i] = 0.f;
}

// ---------------------------------------------------------------------------
// K0: one-shot fp32 -> f16 conversion of the five weight matrices
__global__ void k_cvtall(const float* __restrict__ s0, const float* __restrict__ s1,
                         const float* __restrict__ s2, const float* __restrict__ s3,
                         const float* __restrict__ s4,
                         f16* __restrict__ d0, f16* __restrict__ d1,
                         f16* __restrict__ d2, f16* __restrict__ d3,
                         f16* __restrict__ d4){
  int i = blockIdx.x*256 + threadIdx.x;          // grid covers 196608
  d0[i] = (f16)s0[i];                            // Wih_f  [768*256]
  d1[i] = (f16)s1[i];                            // Wih_b
  d2[i] = (f16)s2[i];                            // Whh_f
  d3[i] = (f16)s3[i];                            // Whh_b
  if (i < 131072) d4[i] = (f16)s4[i];            // W_w    [256*512]
}

// K0b: fp32 -> f16 table conversion, 4 floats/thread (8000 blocks x 256 = 8.192M)
__global__ void k_cvt4(const float* __restrict__ s, f16* __restrict__ d){
  size_t i = ((size_t)blockIdx.x*256 + threadIdx.x)*4;
  float4 v = *(const float4*)(s + i);
  f16x4 o; o[0]=(f16)v.x; o[1]=(f16)v.y; o[2]=(f16)v.z; o[3]=(f16)v.w;
  *(f16x4*)(d + i) = o;
}

// ---------------------------------------------------------------------------
// K1: embed-bag: emb[b*128+t][d] = sum_m emb_ctx[conv[b,t,m]][d]  (f16 out)
__global__ void k_embbag(const int* __restrict__ conv, const float* __restrict__ tbl,
                         f16* __restrict__ emb){
  int bt = blockIdx.x, d = threadIdx.x;
  const int* ix = conv + (size_t)bt*4;
  float s = 0.f;
#pragma unroll
  for (int m = 0; m < 4; ++m) s += tbl[(size_t)ix[m]*256 + d];
  emb[(size_t)bt*256 + d] = (f16)s;
}

// ---------------------------------------------------------------------------
// K2: gx[m=t*32+b][j] = emb_row . Wih[j] + bih[j] + (j<512 ? bhh[j] : 0)
__global__ __launch_bounds__(256) void k_gx(const f16* __restrict__ emb,
                                            const f16* __restrict__ W16,
                                            const float* __restrict__ bih,
                                            const float* __restrict__ bhh,
                                            f16* __restrict__ gx, int rev){
  int lane = threadIdx.x & 63, wv = threadIdx.x >> 6;
  int l16 = lane & 15, l4 = lane >> 4;
  int mrow = blockIdx.x*64 + wv*16;
  int m = mrow + l16;
  int t = m >> 5, b = m & 31;
  int tsrc = rev ? (127 - t) : t;
  const f16* arow = emb + (size_t)(b*128 + tsrc)*256;
  f16x8 af[8];
#pragma unroll
  for (int kt = 0; kt < 8; ++kt) af[kt] = *(const f16x8*)(arow + kt*32 + l4*8);

  for (int nt = 0; nt < 48; ++nt){
    int n = nt*16 + l16;
    const f16* brow = W16 + (size_t)n*256;   // B[k][n] = Wih[n][k]
    f32x4 acc = {0.f,0.f,0.f,0.f};
#pragma unroll
    for (int kt = 0; kt < 8; ++kt){
      f16x8 bf = *(const f16x8*)(brow + kt*32 + l4*8);
      acc = __builtin_amdgcn_mfma_f32_16x16x32_f16(af[kt], bf, acc, 0, 0, 0);
    }
    float bias = bih[n] + (n < 512 ? bhh[n] : 0.f);
#pragma unroll
    for (int r = 0; r < 4; ++r){
      int m2 = mrow + l4*4 + r;
      gx[(size_t)m2*768 + n] = (f16)(acc[r] + bias);
    }
  }
}

// ---------------------------------------------------------------------------
// K3: GRU recurrence. 4 blocks = (dir<<1)|grp16, 512 threads = 8 waves.
// OCCUPANCY PIN (rounds 5-7 lesson): __launch_bounds__ 2nd arg in {none,2,1}
// all produced VGPR_Count=128 => the backend's default 4-waves/EU floor caps
// unified regs at 128 and launch_bounds can only tighten it. The explicit
// amdgpu_waves_per_eu(2,2) attribute pins 2 waves/EU -> 256-reg budget,
// fitting the ~240-reg demand (aW 192 + acc 24 + xg 12 + temps) with no
// scratch spill (the spill reload ~31KB/wave/step was the 383 us).
__global__ __attribute__((amdgpu_flat_work_group_size(512,512), amdgpu_waves_per_eu(2,2)))
void k_gru(const f16* __restrict__ gx_f,
           const f16* __restrict__ gx_b,
           const f16* __restrict__ whhf16,
           const f16* __restrict__ whhb16,
           const float* __restrict__ bhh_f,
           const float* __restrict__ bhh_b,
           f16* __restrict__ Abuf){
  int dir = blockIdx.x >> 1, grp = blockIdx.x & 1, b0 = grp*16;
  const f16*   gx  = dir ? gx_b   : gx_f;
  const f16*   Whh = dir ? whhb16 : whhf16;
  const float* bhh = dir ? bhh_b  : bhh_f;

  int tid = threadIdx.x, lane = tid & 63, wv = tid >> 6;
  int l16 = lane & 15, l4 = lane >> 4;

  __shared__ __align__(16) f16   a16[16][264];   // h f16 [batch][k], +8 pad
  __shared__ __align__(16) float bhnL[256];
  for (int i = tid; i < (16*264*2)/4; i += 512) ((unsigned*)a16)[i] = 0u;  // h0=0
  if (tid < 256) bhnL[tid] = bhh[512 + tid];

  // Whh f16 fragments, gate-aligned rows: wave wv owns Q in {2wv, 2wv+1}
  f16x8 aW[2][3][8];
#pragma unroll
  for (int q = 0; q < 2; ++q){
    int Q = 2*wv + q;
#pragma unroll
    for (int g = 0; g < 3; ++g){
      const f16* wrow = Whh + (size_t)(g*256 + Q*16 + l16)*256;
#pragma unroll
      for (int kt = 0; kt < 8; ++kt) aW[q][g][kt] = *(const f16x8*)(wrow + kt*32 + l4*8);
    }
  }
  const f16* ldsrow = &a16[l16][l4*8];
  const f16* gxbase = gx + (size_t)(b0 + l16)*768;
  f16* abase = Abuf + (size_t)(b0 + l16)*128*512 + dir*256;
  __syncthreads();

#pragma unroll 1
  for (int t = 0; t < 128; ++t){
    const f16* grow = gxbase + (size_t)t*32*768;
    f16x4 xg[2][3];
#pragma unroll
    for (int q = 0; q < 2; ++q)
#pragma unroll
      for (int g = 0; g < 3; ++g)
        xg[q][g] = *(const f16x4*)(grow + g*256 + (2*wv+q)*16 + l4*4);

    f32x4 acc[2][3];
#pragma unroll
    for (int q = 0; q < 2; ++q)
#pragma unroll
      for (int g = 0; g < 3; ++g) acc[q][g] = (f32x4){0.f,0.f,0.f,0.f};

#pragma unroll
    for (int kt = 0; kt < 8; ++kt){
      f16x8 bf = *(const f16x8*)(ldsrow + kt*32);   // B[k][n=batch]
#pragma unroll
      for (int q = 0; q < 2; ++q)
#pragma unroll
        for (int g = 0; g < 3; ++g)
          acc[q][g] = __builtin_amdgcn_mfma_f32_16x16x32_f16(aW[q][g][kt], bf, acc[q][g], 0, 0, 0);
    }
    __syncthreads();   // all B-frag reads of a16 complete before overwrite

    int trow = dir ? (127 - t) : t;
#pragma unroll
    for (int q = 0; q < 2; ++q){
      int d0 = (2*wv+q)*16 + l4*4;
      float4 bh4 = *(const float4*)(&bhnL[d0]);
      f16x4 hold = *(const f16x4*)(&a16[l16][d0]);   // own slot only
      f16x4 o4;
#pragma unroll
      for (int r = 0; r < 4; ++r){
        float bh = (r==0)?bh4.x:(r==1)?bh4.y:(r==2)?bh4.z:bh4.w;
        float rr = fsig ((float)xg[q][0][r] + acc[q][0][r]);
        float zz = fsig ((float)xg[q][1][r] + acc[q][1][r]);
        float nn = ftanh((float)xg[q][2][r] + rr*(acc[q][2][r] + bh));
        float h2 = nn + zz*((float)hold[r] - nn);
        o4[r] = (f16)h2;
      }
      *(f16x4*)(&a16[l16][d0]) = o4;
      // ys (f16): fwd -> cols 0:256 at row b*128+t; bwd -> cols 256:512 at 127-t
      *(f16x4*)(abase + (size_t)trow*512 + d0) = o4;
    }
    __syncthreads();   // a16 ready for next step
  }
}

// ---------------------------------------------------------------------------
// K4: rnn_out[m][n] = Abuf[m] . W_w[n] + W_b[n]   (K=512; all-f16 operands)
__global__ __launch_bounds__(256) void k_rnnout(const f16* __restrict__ Abuf,
                                                const f16* __restrict__ Ww16,
                                                const float* __restrict__ Wb,
                                                float* __restrict__ rnn){
  int lane = threadIdx.x & 63, wv = threadIdx.x >> 6;
  int l16 = lane & 15, l4 = lane >> 4;
  int mrow = blockIdx.x*64 + wv*16;
  const f16* arow = Abuf + (size_t)(mrow + l16)*512;
  f16x8 af[16];
#pragma unroll
  for (int kt = 0; kt < 16; ++kt) af[kt] = *(const f16x8*)(arow + kt*32 + l4*8);
  for (int nt = 0; nt < 16; ++nt){
    int n = nt*16 + l16;
    const f16* brow = Ww16 + (size_t)n*512;
    f32x4 acc = {0.f,0.f,0.f,0.f};
#pragma unroll
    for (int kt = 0; kt < 16; ++kt){
      f16x8 bf = *(const f16x8*)(brow + kt*32 + l4*8);
      acc = __builtin_amdgcn_mfma_f32_16x16x32_f16(af[kt], bf, acc, 0, 0, 0);
    }
    float bias = Wb[n];
#pragma unroll
    for (int r = 0; r < 4; ++r)
      rnn[(size_t)(mrow + l4*4 + r)*256 + n] = acc[r] + bias;
  }
}

// ---------------------------------------------------------------------------
// K5: hidden/u = concat(hT_f, hT_b) . W_w^T + W_b  via MFMA (M=32,N=256,K=512)
__global__ __launch_bounds__(256) void k_hidden(const f16* __restrict__ Abuf,
                                                const f16* __restrict__ Ww16,
                                                const float* __restrict__ Wb,
                                                float* __restrict__ hidden,
                                                float* __restrict__ u){
  int lane = threadIdx.x & 63, wv = threadIdx.x >> 6;
  int l16 = lane & 15, l4 = lane >> 4;
  int mt = wv & 1, nt = blockIdx.x*2 + (wv >> 1);
  int b = mt*16 + l16;
  const f16* rowf = Abuf + ((size_t)b*128 + 127)*512;
  const f16* rowb = Abuf + ((size_t)b*128)*512;
  f16x8 af[16];
#pragma unroll
  for (int kt = 0; kt < 16; ++kt){
    int k = kt*32 + l4*8;
    af[kt] = *(const f16x8*)((k < 256 ? rowf : rowb) + k);
  }
  int n = nt*16 + l16;
  const f16* brow = Ww16 + (size_t)n*512;
  f32x4 acc = {0.f,0.f,0.f,0.f};
#pragma unroll
  for (int kt = 0; kt < 16; ++kt){
    f16x8 bf = *(const f16x8*)(brow + kt*32 + l4*8);
    acc = __builtin_amdgcn_mfma_f32_16x16x32_f16(af[kt], bf, acc, 0, 0, 0);
  }
  float bias = Wb[n];
#pragma unroll
  for (int r = 0; r < 4; ++r){
    int bo = mt*16 + l4*4 + r;
    float v = acc[r] + bias;
    hidden[(size_t)bo*256 + n] = v;
    u[(size_t)bo*256 + n] = v;
  }
}

// ---------------------------------------------------------------------------
// K6a: logits[b][l] = (sum_m tbl16[src[b,l,m]] + lm_add) . u[b]   (f16 table)
__global__ __launch_bounds__(256) void k_logits(const int* __restrict__ src,
                                                const int* __restrict__ kbl,
                                                const int* __restrict__ cvl,
                                                const f16* __restrict__ tbl,
                                                const float* __restrict__ rnn,
                                                const float* __restrict__ u,
                                                float* __restrict__ logits){
  int b = blockIdx.x >> 5, chunk = blockIdx.x & 31;
  int lane = threadIdx.x & 63, wv = threadIdx.x >> 6;
  int kb = kbl[b], cl = cvl[b];
  float4 uv = *(const float4*)(u + b*256 + lane*4);
#pragma unroll
  for (int i = 0; i < 4; ++i){
    int l = chunk*16 + wv*4 + i;
    const int* sp = src + ((size_t)b*512 + l)*4;
    float b0 = 0.f, b1 = 0.f, b2 = 0.f, b3 = 0.f;
#pragma unroll
    for (int m = 0; m < 4; ++m){
      f16x4 wq = *(const f16x4*)(tbl + (size_t)sp[m]*256 + lane*4);
      b0 += (float)wq[0]; b1 += (float)wq[1]; b2 += (float)wq[2]; b3 += (float)wq[3];
    }
    int rel = l - kb;
    if (rel >= 0 && rel < cl){
      int rc = rel < 127 ? rel : 127;
      float4 rv = *(const float4*)(rnn + ((size_t)b*128 + rc)*256 + lane*4);
      b0 += rv.x; b1 += rv.y; b2 += rv.z; b3 += rv.w;
    }
    float p = b0*uv.x + b1*uv.y + b2*uv.z + b3*uv.w;
#pragma unroll
    for (int off = 32; off >= 1; off >>= 1) p += __shfl_down(p, off);
    if (lane == 0) logits[(size_t)b*512 + l] = p;
  }
}

// ---------------------------------------------------------------------------
// K6b: fused softmax + o_k accumulate (f16 table). 256 blocks = (b<<3)|chunk.
// On the last hop, chunk-0 blocks also emit global_pointer = sigmoid(logits).
__global__ __launch_bounds__(256) void k_okv(const int* __restrict__ src,
                                             const int* __restrict__ kbl,
                                             const int* __restrict__ cvl,
                                             const f16* __restrict__ tbl,
                                             const float* __restrict__ rnn,
                                             const float* __restrict__ logits,
                                             float* __restrict__ u,
                                             float* __restrict__ gp_out, int write_gp){
  int b = blockIdx.x >> 3, c = blockIdx.x & 7;
  int d = threadIdx.x, lane = d & 63, wv = d >> 6;
  __shared__ float red[4];
  __shared__ float bc;
  __shared__ float pr[512];
  __shared__ int   sidx[256];

  float v0 = logits[(size_t)b*512 + d];
  float v1 = logits[(size_t)b*512 + 256 + d];
  float m = fmaxf(v0, v1);
#pragma unroll
  for (int off = 32; off >= 1; off >>= 1) m = fmaxf(m, __shfl_down(m, off));
  if (lane == 0) red[wv] = m;
  __syncthreads();
  if (d == 0) bc = fmaxf(fmaxf(red[0], red[1]), fmaxf(red[2], red[3]));
  __syncthreads();
  float mx = bc;
  float e0 = __expf(v0 - mx), e1 = __expf(v1 - mx);
  float s = e0 + e1;
#pragma unroll
  for (int off = 32; off >= 1; off >>= 1) s += __shfl_down(s, off);
  __syncthreads();
  if (lane == 0) red[wv] = s;
  __syncthreads();
  if (d == 0) bc = red[0] + red[1] + red[2] + red[3];
  __syncthreads();
  float inv = 1.0f/bc;
  pr[d] = e0*inv; pr[256 + d] = e1*inv;
  sidx[d] = src[(size_t)b*2048 + c*256 + d];
  if (write_gp && c == 0){
    gp_out[(size_t)b*512 + d]       = fsig(v0);
    gp_out[(size_t)b*512 + 256 + d] = fsig(v1);
  }
  __syncthreads();

  int kb = kbl[b], cl = cvl[b];
  float acc = 0.f;
  for (int l = 0; l < 64; ++l){
    const int* sp = sidx + l*4;
    float bag = (float)tbl[(size_t)sp[0]*256 + d] + (float)tbl[(size_t)sp[1]*256 + d]
              + (float)tbl[(size_t)sp[2]*256 + d] + (float)tbl[(size_t)sp[3]*256 + d];
    int rel = (c*64 + l) - kb;
    if (rel >= 0 && rel < cl){
      int rc = rel < 127 ? rel : 127;
      bag += rnn[((size_t)b*128 + rc)*256 + d];
    }
    acc += pr[c*64 + l] * bag;
  }
  atomicAdd(&u[(size_t)b*256 + d], acc);
}

// ---------------------------------------------------------------------------
// K7: encoded[b][d] = relu(concat(hidden,u) . proj_w[d] + proj_b[d])  (fp32)
__global__ void k_encoded(const float* __restrict__ hidden, const float* __restrict__ u,
                          const float* __restrict__ pw, const float* __restrict__ pb,
                          float* __restrict__ out){
  int b = blockIdx.x, d = threadIdx.x;
  const float* w = pw + (size_t)d*512;
  float s = pb[d];
  for (int k = 0; k < 256; ++k) s += hidden[b*256 + k] * w[k];
  for (int k = 0; k < 256; ++k) s += u[b*256 + k]      * w[256 + k];
  out[(size_t)b*256 + d] = fmaxf(s, 0.f);
}

// ---------------------------------------------------------------------------
extern "C" void kernel_launch(void* const* d_in, const int* in_sizes, int n_in,
                              void* d_out, int out_size, void* d_ws, size_t ws_size,
                              hipStream_t stream){
  (void)in_sizes; (void)n_in; (void)out_size;
  float* out = (float*)d_out;  // [0:16384) global_pointer, [16384:24576) encoded

  const size_t WS_NEEDED = 25034752;
  if (ws_size < WS_NEEDED){
    k_zero<<<96, 256, 0, stream>>>(out);
    return;
  }

  const int* conv  = (const int*)d_in[0];
  const int* src   = (const int*)d_in[1];
  const int* kbl   = (const int*)d_in[2];
  const int* cvl   = (const int*)d_in[3];
  const float* emb_ctx = (const float*)d_in[4];
  const float* Ct      = (const float*)d_in[5];
  const float* Wih_f = (const float*)d_in[6];
  const float* Whh_f = (const float*)d_in[7];
  const float* bih_f = (const float*)d_in[8];
  const float* bhh_f = (const float*)d_in[9];
  const float* Wih_b = (const float*)d_in[10];
  const float* Whh_b = (const float*)d_in[11];
  const float* bih_b = (const float*)d_in[12];
  const float* bhh_b = (const float*)d_in[13];
  const float* Ww = (const float*)d_in[14];
  const float* Wb = (const float*)d_in[15];
  const float* pw = (const float*)d_in[16];
  const float* pb = (const float*)d_in[17];

  char* ws = (char*)d_ws;
  f16*   emb    = (f16*)(ws);                  //  2,097,152  [4096][256] f16
  f16*   gx_f   = (f16*)(ws + 2097152);        //  6,291,456  [t*32+b][768] f16
  f16*   gx_b   = (f16*)(ws + 8388608);        //  6,291,456
  f16*   Abuf   = (f16*)(ws + 14680064);       //  4,194,304  [b*128+t][512] f16
  float* rnn    = (float*)(ws + 18874368);     //  4,194,304  [b*128+t][256] f32
  float* hidden = (float*)(ws + 23068672);     //     32,768
  float* u      = (float*)(ws + 23101440);     //     32,768
  float* logits = (float*)(ws + 23134208);     //     65,536
  f16*   wihf16 = (f16*)(ws + 23199744);       //    393,216  [768][256]
  f16*   wihb16 = (f16*)(ws + 23592960);       //    393,216
  f16*   whhf16 = (f16*)(ws + 23986176);       //    393,216
  f16*   whhb16 = (f16*)(ws + 24379392);       //    393,216
  f16*   ww16   = (f16*)(ws + 24772608);       //    262,144  [256][512]
                                               // end 25,034,752
  // f16 table buffer (16,384,000 B) ALIASES emb/gx_f/gx_b/Abuf-head — all dead
  // once the hop loop starts (k_hidden is the last reader of Abuf).
  f16*   Ct16   = (f16*)(ws);

  k_cvtall<<<768, 256, 0, stream>>>(Wih_f, Wih_b, Whh_f, Whh_b, Ww,
                                    wihf16, wihb16, whhf16, whhb16, ww16);
  k_embbag<<<4096, 256, 0, stream>>>(conv, emb_ctx, emb);
  k_gx<<<64, 256, 0, stream>>>(emb, wihf16, bih_f, bhh_f, gx_f, 0);
  k_gx<<<64, 256, 0, stream>>>(emb, wihb16, bih_b, bhh_b, gx_b, 1);
  k_gru<<<4, 512, 0, stream>>>(gx_f, gx_b, whhf16, whhb16, bhh_f, bhh_b, Abuf);
  k_rnnout<<<64, 256, 0, stream>>>(Abuf, ww16, Wb, rnn);
  k_hidden<<<8, 256, 0, stream>>>(Abuf, ww16, Wb, hidden, u);

  // Hop loop: convert each table to f16 once, use for okv(hop) and logits(hop+1)
  const size_t TBL = 32000ull * 256ull;
  k_cvt4<<<8000, 256, 0, stream>>>(Ct, Ct16);
  k_logits<<<1024, 256, 0, stream>>>(src, kbl, cvl, Ct16, rnn, u, logits);
  for (int hop = 0; hop < 3; ++hop){
    k_cvt4<<<8000, 256, 0, stream>>>(Ct + (size_t)(hop + 1)*TBL, Ct16);
    k_okv<<<256, 256, 0, stream>>>(src, kbl, cvl, Ct16, rnn, logits, u,
                                   out, hop == 2 ? 1 : 0);
    if (hop < 2)
      k_logits<<<1024, 256, 0, stream>>>(src, kbl, cvl, Ct16, rnn, u, logits);
  }
  k_encoded<<<32, 256, 0, stream>>>(hidden, u, pw, pb, out + 16384);
}